// Round 1
// baseline (5326.538 us; speedup 1.0000x reference)
//
#include <hip/hip_runtime.h>
#include <math.h>

// Problem dims (fixed by reference)
#define CC 4
#define FE 32
#define HH 64
#define EBS 256   // edge-kernel block size

// ---------------------------------------------------------------------------
// Kernel A: x[n,c,j] = sum_{i,a} node_input[n,c,i] * node_attr[n,a] * W_lin1[i,a,j]
// one thread per (n,c)
// ---------------------------------------------------------------------------
__global__ __launch_bounds__(256) void k_lin1(
    const float* __restrict__ node_input, const float* __restrict__ node_attr,
    const float* __restrict__ W_lin1, float* __restrict__ xout, int n_nc)
{
    int t = blockIdx.x * 256 + threadIdx.x;
    if (t >= n_nc) return;
    int n = t >> 2;
    float attr[16];
    #pragma unroll
    for (int a = 0; a < 16; ++a) attr[a] = node_attr[(size_t)n * 16 + a];
    float xi[8];
    #pragma unroll
    for (int i = 0; i < 8; ++i) xi[i] = node_input[(size_t)t * 8 + i];
    float xo[8] = {0.f, 0.f, 0.f, 0.f, 0.f, 0.f, 0.f, 0.f};
    #pragma unroll
    for (int i = 0; i < 8; ++i) {
        #pragma unroll
        for (int a = 0; a < 16; ++a) {
            float f = xi[i] * attr[a];
            #pragma unroll
            for (int j = 0; j < 8; ++j)
                xo[j] += f * W_lin1[(i * 16 + a) * 8 + j];
        }
    }
    #pragma unroll
    for (int j = 0; j < 8; ++j) xout[(size_t)t * 8 + j] = xo[j];
}

// ---------------------------------------------------------------------------
// Kernel B: per-edge radial MLP + contraction + atomic scatter into agg(=out)
//   h  = silu(ef @ fc_w1 + b1)                       [64]
//   t_d = b2[d,:] + h @ fc_w2[:, d,:,:]              [64] per d
//   msg[c,d,o] = sum_i x[src,c,i] * t_d[i*8+o]
//   atomicAdd(agg[dst, c, d, o], msg)
// one thread per edge; W1/W2/b loads are wave-uniform (one transaction / wave)
// ---------------------------------------------------------------------------
__global__ __launch_bounds__(EBS) void k_edge(
    const float* __restrict__ edge_features,
    const float* __restrict__ fc_w1, const float* __restrict__ fc_b1,
    const float* __restrict__ fc_w2, const float* __restrict__ fc_b2,
    const int* __restrict__ edge_src, const int* __restrict__ edge_dst,
    const float* __restrict__ xin, float* __restrict__ agg, int E)
{
    __shared__ float hlds[HH * EBS];   // [k][tid] layout: conflict-free
    int e = blockIdx.x * EBS + threadIdx.x;
    if (e >= E) return;

    // ---- radial MLP layer 1 (h in registers, fully static indexing) ----
    float h[HH];
    #pragma unroll
    for (int k = 0; k < HH; ++k) h[k] = fc_b1[k];
    const float4* efp = reinterpret_cast<const float4*>(edge_features + (size_t)e * FE);
    #pragma unroll
    for (int fq = 0; fq < FE / 4; ++fq) {
        float4 efv = efp[fq];
        float ev[4] = {efv.x, efv.y, efv.z, efv.w};
        #pragma unroll
        for (int fs = 0; fs < 4; ++fs) {
            float evv = ev[fs];
            const float4* w1p = reinterpret_cast<const float4*>(fc_w1 + (fq * 4 + fs) * HH);
            #pragma unroll
            for (int q = 0; q < HH / 4; ++q) {
                float4 w = w1p[q];
                h[q * 4 + 0] += evv * w.x;
                h[q * 4 + 1] += evv * w.y;
                h[q * 4 + 2] += evv * w.z;
                h[q * 4 + 3] += evv * w.w;
            }
        }
    }
    // silu -> LDS (own column; no cross-thread sharing, no barrier needed)
    #pragma unroll
    for (int k = 0; k < HH; ++k) {
        float v = h[k];
        hlds[k * EBS + threadIdx.x] = v / (1.f + __expf(-v));
    }

    int src = edge_src[e], dst = edge_dst[e];
    float xs[32];
    const float4* xp = reinterpret_cast<const float4*>(xin + (size_t)src * 32);
    #pragma unroll
    for (int q = 0; q < 8; ++q) {
        float4 v = xp[q];
        xs[q * 4 + 0] = v.x; xs[q * 4 + 1] = v.y;
        xs[q * 4 + 2] = v.z; xs[q * 4 + 3] = v.w;
    }
    float* outp = agg + (size_t)dst * 256;

    #pragma unroll 1
    for (int d = 0; d < 8; ++d) {
        float t[64];
        const float4* b2p = reinterpret_cast<const float4*>(fc_b2 + d * 64);
        #pragma unroll
        for (int q = 0; q < 16; ++q) {
            float4 v = b2p[q];
            t[q * 4 + 0] = v.x; t[q * 4 + 1] = v.y;
            t[q * 4 + 2] = v.z; t[q * 4 + 3] = v.w;
        }
        // t += h @ W2[:, d-slice]  (W2 loads wave-uniform)
        for (int k = 0; k < HH; ++k) {
            float hv = hlds[k * EBS + threadIdx.x];
            const float4* wp = reinterpret_cast<const float4*>(fc_w2 + (size_t)k * 512 + d * 64);
            #pragma unroll
            for (int q = 0; q < 16; ++q) {
                float4 w = wp[q];
                t[q * 4 + 0] += hv * w.x;
                t[q * 4 + 1] += hv * w.y;
                t[q * 4 + 2] += hv * w.z;
                t[q * 4 + 3] += hv * w.w;
            }
        }
        // msg + scatter
        #pragma unroll
        for (int c = 0; c < CC; ++c) {
            #pragma unroll
            for (int o = 0; o < 8; ++o) {
                float acc = 0.f;
                #pragma unroll
                for (int i = 0; i < 8; ++i) acc += xs[c * 8 + i] * t[i * 8 + o];
                atomicAdd(outp + c * 64 + d * 8 + o, acc);
            }
        }
    }
}

// ---------------------------------------------------------------------------
// Kernel C: per (n,c): out[n,c,d,p] = c_s * s[n,c,p]
//                     + c_x * (1/sqrt(8)) * sum_o agg[n,c,d,o] * W2n[o,p]
// where W2n[o,p] = sum_a attr[n,a]*W_lin2[o,a,p],
//       s[n,c,o] = sum_{i,a} node_input[n,c,i]*attr[n,a]*W_sc[i,a,o]
// reads agg from `out` in place, writes final values back.
// ---------------------------------------------------------------------------
__global__ __launch_bounds__(256) void k_node_out(
    const float* __restrict__ node_input, const float* __restrict__ node_attr,
    const float* __restrict__ W_sc, const float* __restrict__ W_lin2,
    float* __restrict__ out, int n_nc)
{
    const float c_s = 0.3826834323650898f;
    const float c_x_scaled = 0.9238795325112867f * 0.35355339059327373f; // c_x / sqrt(8)
    int t = blockIdx.x * 256 + threadIdx.x;
    if (t >= n_nc) return;
    int n = t >> 2;
    float attr[16];
    #pragma unroll
    for (int a = 0; a < 16; ++a) attr[a] = node_attr[(size_t)n * 16 + a];

    // W2n[o][p]
    float w2n[64];
    #pragma unroll
    for (int m = 0; m < 64; ++m) w2n[m] = 0.f;
    #pragma unroll
    for (int o = 0; o < 8; ++o) {
        #pragma unroll
        for (int a = 0; a < 16; ++a) {
            float fa = attr[a];
            #pragma unroll
            for (int p = 0; p < 8; ++p)
                w2n[o * 8 + p] += fa * W_lin2[(o * 16 + a) * 8 + p];
        }
    }
    // s[o]
    float s[8] = {0.f, 0.f, 0.f, 0.f, 0.f, 0.f, 0.f, 0.f};
    #pragma unroll
    for (int i = 0; i < 8; ++i) {
        float vi = node_input[(size_t)t * 8 + i];
        #pragma unroll
        for (int a = 0; a < 16; ++a) {
            float f = vi * attr[a];
            #pragma unroll
            for (int o = 0; o < 8; ++o)
                s[o] += f * W_sc[(i * 16 + a) * 8 + o];
        }
    }
    float* rowp = out + (size_t)t * 64;
    #pragma unroll 1
    for (int d = 0; d < 8; ++d) {
        float aggv[8];
        #pragma unroll
        for (int o = 0; o < 8; ++o) aggv[o] = rowp[d * 8 + o];
        #pragma unroll
        for (int p = 0; p < 8; ++p) {
            float acc = 0.f;
            #pragma unroll
            for (int o = 0; o < 8; ++o) acc += aggv[o] * w2n[o * 8 + p];
            rowp[d * 8 + p] = c_s * s[p] + c_x_scaled * acc;
        }
    }
}

// ---------------------------------------------------------------------------
extern "C" void kernel_launch(void* const* d_in, const int* in_sizes, int n_in,
                              void* d_out, int out_size, void* d_ws, size_t ws_size,
                              hipStream_t stream)
{
    const float* node_input    = (const float*)d_in[0];
    const float* node_attr     = (const float*)d_in[1];
    const float* edge_features = (const float*)d_in[2];
    const float* W_sc          = (const float*)d_in[3];
    const float* W_lin1        = (const float*)d_in[4];
    const float* W_lin2        = (const float*)d_in[5];
    const float* fc_w1         = (const float*)d_in[6];
    const float* fc_b1         = (const float*)d_in[7];
    const float* fc_w2         = (const float*)d_in[8];
    const float* fc_b2         = (const float*)d_in[9];
    const int*   edge_src      = (const int*)d_in[10];
    const int*   edge_dst      = (const int*)d_in[11];

    const int N = in_sizes[1] / 16;        // node count
    const int E = in_sizes[10];            // edge count
    const int n_nc = N * CC;

    float* xbuf = (float*)d_ws;            // [N, C, 8] = N*32 floats
    float* out  = (float*)d_out;           // used as agg accumulator, then finalized

    // zero the aggregation buffer (out) — harness does not re-poison between replays
    hipMemsetAsync(d_out, 0, (size_t)out_size * sizeof(float), stream);

    // node prep: x = lin1(node_input, node_attr)
    k_lin1<<<(n_nc + 255) / 256, 256, 0, stream>>>(node_input, node_attr, W_lin1, xbuf, n_nc);

    // edge kernel: radial MLP + contraction + scatter
    k_edge<<<(E + EBS - 1) / EBS, EBS, 0, stream>>>(
        edge_features, fc_w1, fc_b1, fc_w2, fc_b2, edge_src, edge_dst, xbuf, out, E);

    // node output: lin2 + self-connection combine (in-place on out)
    k_node_out<<<(n_nc + 255) / 256, 256, 0, stream>>>(node_input, node_attr, W_sc, W_lin2, out, n_nc);
}

// Round 2
// 1111.367 us; speedup vs baseline: 4.7928x; 4.7928x over previous
//
#include <hip/hip_runtime.h>
#include <math.h>

// Problem dims (fixed by reference)
#define CC 4
#define FE 32
#define HH 64
#define EBS 256   // edge-kernel block size

// bf16 round-to-nearest-even pack (values are finite; no NaN handling needed)
__device__ inline unsigned short f2bf(float f) {
    unsigned u = __float_as_uint(f);
    u += 0x7fffu + ((u >> 16) & 1u);
    return (unsigned short)(u >> 16);
}
__device__ inline float bf2f(unsigned short b) {
    return __uint_as_float(((unsigned)b) << 16);
}

// ---------------------------------------------------------------------------
// Kernel A: x[n,c,j] = sum_{i,a} node_input[n,c,i] * node_attr[n,a] * W_lin1[i,a,j]
// ---------------------------------------------------------------------------
__global__ __launch_bounds__(256) void k_lin1(
    const float* __restrict__ node_input, const float* __restrict__ node_attr,
    const float* __restrict__ W_lin1, float* __restrict__ xout, int n_nc)
{
    int t = blockIdx.x * 256 + threadIdx.x;
    if (t >= n_nc) return;
    int n = t >> 2;
    float attr[16];
    #pragma unroll
    for (int a = 0; a < 16; ++a) attr[a] = node_attr[(size_t)n * 16 + a];
    float xi[8];
    #pragma unroll
    for (int i = 0; i < 8; ++i) xi[i] = node_input[(size_t)t * 8 + i];
    float xo[8] = {0.f, 0.f, 0.f, 0.f, 0.f, 0.f, 0.f, 0.f};
    #pragma unroll
    for (int i = 0; i < 8; ++i) {
        #pragma unroll
        for (int a = 0; a < 16; ++a) {
            float f = xi[i] * attr[a];
            #pragma unroll
            for (int j = 0; j < 8; ++j)
                xo[j] += f * W_lin1[(i * 16 + a) * 8 + j];
        }
    }
    #pragma unroll
    for (int j = 0; j < 8; ++j) xout[(size_t)t * 8 + j] = xo[j];
}

// ---------------------------------------------------------------------------
// CSR build: histogram -> exclusive scan -> fill permutation
// ---------------------------------------------------------------------------
__global__ __launch_bounds__(256) void k_hist(
    const int* __restrict__ edge_dst, int* __restrict__ counts, int E)
{
    int e = blockIdx.x * 256 + threadIdx.x;
    if (e < E) atomicAdd(&counts[edge_dst[e]], 1);
}

__global__ __launch_bounds__(1024) void k_scan(
    const int* __restrict__ counts, int* __restrict__ offsets,
    int* __restrict__ cursor, int N)
{
    __shared__ int buf[1024];
    __shared__ int s_carry;
    int tid = threadIdx.x;
    if (tid == 0) s_carry = 0;
    __syncthreads();
    for (int base = 0; base < N; base += 1024) {
        int idx = base + tid;
        int v = (idx < N) ? counts[idx] : 0;
        buf[tid] = v;
        __syncthreads();
        #pragma unroll 1
        for (int s = 1; s < 1024; s <<= 1) {
            int add = (tid >= s) ? buf[tid - s] : 0;
            __syncthreads();
            buf[tid] += add;
            __syncthreads();
        }
        int incl = buf[tid];
        int carry = s_carry;
        if (idx < N) {
            int excl = carry + incl - v;
            offsets[idx] = excl;
            cursor[idx] = excl;
        }
        __syncthreads();
        if (tid == 1023) s_carry = carry + incl;  // incl of last thread = tile total
        __syncthreads();
    }
}

__global__ __launch_bounds__(256) void k_fill(
    const int* __restrict__ edge_dst, int* __restrict__ cursor,
    int* __restrict__ perm, int E)
{
    int e = blockIdx.x * 256 + threadIdx.x;
    if (e < E) {
        int pos = atomicAdd(&cursor[edge_dst[e]], 1);
        perm[pos] = e;
    }
}

// ---------------------------------------------------------------------------
// Kernel B (fast path): per-edge radial MLP + contraction, stream msg as bf16.
// No atomics. W1/W2/b loads are wave-uniform (one transaction per wave).
// ---------------------------------------------------------------------------
__global__ __launch_bounds__(EBS) void k_edge_msg(
    const float* __restrict__ edge_features,
    const float* __restrict__ fc_w1, const float* __restrict__ fc_b1,
    const float* __restrict__ fc_w2, const float* __restrict__ fc_b2,
    const int* __restrict__ edge_src,
    const float* __restrict__ xin, unsigned short* __restrict__ msg, int E)
{
    __shared__ unsigned short hlds[HH * EBS];   // bf16 h, [k][tid]: 32 KB
    int e = blockIdx.x * EBS + threadIdx.x;
    if (e >= E) return;

    // ---- radial MLP layer 1 ----
    float h[HH];
    #pragma unroll
    for (int k = 0; k < HH; ++k) h[k] = fc_b1[k];
    const float4* efp = reinterpret_cast<const float4*>(edge_features + (size_t)e * FE);
    #pragma unroll
    for (int fq = 0; fq < FE / 4; ++fq) {
        float4 efv = efp[fq];
        float ev[4] = {efv.x, efv.y, efv.z, efv.w};
        #pragma unroll
        for (int fs = 0; fs < 4; ++fs) {
            float evv = ev[fs];
            const float4* w1p = reinterpret_cast<const float4*>(fc_w1 + (fq * 4 + fs) * HH);
            #pragma unroll
            for (int q = 0; q < HH / 4; ++q) {
                float4 w = w1p[q];
                h[q * 4 + 0] += evv * w.x;
                h[q * 4 + 1] += evv * w.y;
                h[q * 4 + 2] += evv * w.z;
                h[q * 4 + 3] += evv * w.w;
            }
        }
    }
    #pragma unroll
    for (int k = 0; k < HH; ++k) {
        float v = h[k];
        hlds[k * EBS + threadIdx.x] = f2bf(v / (1.f + __expf(-v)));
    }

    int src = edge_src[e];
    float xs[32];
    const float4* xp = reinterpret_cast<const float4*>(xin + (size_t)src * 32);
    #pragma unroll
    for (int q = 0; q < 8; ++q) {
        float4 v = xp[q];
        xs[q * 4 + 0] = v.x; xs[q * 4 + 1] = v.y;
        xs[q * 4 + 2] = v.z; xs[q * 4 + 3] = v.w;
    }
    unsigned short* mrow = msg + (size_t)e * 256;

    #pragma unroll 1
    for (int d = 0; d < 8; ++d) {
        float t[64];
        const float4* b2p = reinterpret_cast<const float4*>(fc_b2 + d * 64);
        #pragma unroll
        for (int q = 0; q < 16; ++q) {
            float4 v = b2p[q];
            t[q * 4 + 0] = v.x; t[q * 4 + 1] = v.y;
            t[q * 4 + 2] = v.z; t[q * 4 + 3] = v.w;
        }
        for (int k = 0; k < HH; ++k) {
            float hv = bf2f(hlds[k * EBS + threadIdx.x]);
            const float4* wp = reinterpret_cast<const float4*>(fc_w2 + (size_t)k * 512 + d * 64);
            #pragma unroll
            for (int q = 0; q < 16; ++q) {
                float4 w = wp[q];
                t[q * 4 + 0] += hv * w.x;
                t[q * 4 + 1] += hv * w.y;
                t[q * 4 + 2] += hv * w.z;
                t[q * 4 + 3] += hv * w.w;
            }
        }
        #pragma unroll
        for (int c = 0; c < CC; ++c) {
            float acc[8];
            #pragma unroll
            for (int o = 0; o < 8; ++o) {
                float a = 0.f;
                #pragma unroll
                for (int i = 0; i < 8; ++i) a += xs[c * 8 + i] * t[i * 8 + o];
                acc[o] = a;
            }
            uint4 pk;
            pk.x = (unsigned)f2bf(acc[0]) | ((unsigned)f2bf(acc[1]) << 16);
            pk.y = (unsigned)f2bf(acc[2]) | ((unsigned)f2bf(acc[3]) << 16);
            pk.z = (unsigned)f2bf(acc[4]) | ((unsigned)f2bf(acc[5]) << 16);
            pk.w = (unsigned)f2bf(acc[6]) | ((unsigned)f2bf(acc[7]) << 16);
            reinterpret_cast<uint4*>(mrow)[c * 8 + d] = pk;
        }
    }
}

// ---------------------------------------------------------------------------
// Gather: one wave per node; lane owns 4 consecutive (c,d,o) elements.
// Reads msg[perm[j]] rows (512B coalesced per row), plain stores to agg(=out).
// ---------------------------------------------------------------------------
__global__ __launch_bounds__(256) void k_gather(
    const unsigned short* __restrict__ msg, const int* __restrict__ perm,
    const int* __restrict__ offsets, const int* __restrict__ counts,
    float* __restrict__ out, int N)
{
    int node = blockIdx.x * 4 + (threadIdx.x >> 6);
    int lane = threadIdx.x & 63;
    if (node >= N) return;
    int off = offsets[node];
    int cnt = counts[node];
    float a0 = 0.f, a1 = 0.f, a2 = 0.f, a3 = 0.f;
    for (int j = 0; j < cnt; ++j) {
        int e = perm[off + j];
        ushort4 v = reinterpret_cast<const ushort4*>(msg + (size_t)e * 256)[lane];
        a0 += bf2f(v.x); a1 += bf2f(v.y); a2 += bf2f(v.z); a3 += bf2f(v.w);
    }
    float4 r; r.x = a0; r.y = a1; r.z = a2; r.w = a3;
    reinterpret_cast<float4*>(out + (size_t)node * 256)[lane] = r;
}

// ---------------------------------------------------------------------------
// Fallback edge kernel (global atomics) — used only if ws_size is too small.
// ---------------------------------------------------------------------------
__global__ __launch_bounds__(EBS) void k_edge_atomic(
    const float* __restrict__ edge_features,
    const float* __restrict__ fc_w1, const float* __restrict__ fc_b1,
    const float* __restrict__ fc_w2, const float* __restrict__ fc_b2,
    const int* __restrict__ edge_src, const int* __restrict__ edge_dst,
    const float* __restrict__ xin, float* __restrict__ agg, int E)
{
    __shared__ float hlds[HH * EBS];
    int e = blockIdx.x * EBS + threadIdx.x;
    if (e >= E) return;
    float h[HH];
    #pragma unroll
    for (int k = 0; k < HH; ++k) h[k] = fc_b1[k];
    const float4* efp = reinterpret_cast<const float4*>(edge_features + (size_t)e * FE);
    #pragma unroll
    for (int fq = 0; fq < FE / 4; ++fq) {
        float4 efv = efp[fq];
        float ev[4] = {efv.x, efv.y, efv.z, efv.w};
        #pragma unroll
        for (int fs = 0; fs < 4; ++fs) {
            float evv = ev[fs];
            const float4* w1p = reinterpret_cast<const float4*>(fc_w1 + (fq * 4 + fs) * HH);
            #pragma unroll
            for (int q = 0; q < HH / 4; ++q) {
                float4 w = w1p[q];
                h[q * 4 + 0] += evv * w.x;
                h[q * 4 + 1] += evv * w.y;
                h[q * 4 + 2] += evv * w.z;
                h[q * 4 + 3] += evv * w.w;
            }
        }
    }
    #pragma unroll
    for (int k = 0; k < HH; ++k) {
        float v = h[k];
        hlds[k * EBS + threadIdx.x] = v / (1.f + __expf(-v));
    }
    int src = edge_src[e], dst = edge_dst[e];
    float xs[32];
    const float4* xp = reinterpret_cast<const float4*>(xin + (size_t)src * 32);
    #pragma unroll
    for (int q = 0; q < 8; ++q) {
        float4 v = xp[q];
        xs[q * 4 + 0] = v.x; xs[q * 4 + 1] = v.y;
        xs[q * 4 + 2] = v.z; xs[q * 4 + 3] = v.w;
    }
    float* outp = agg + (size_t)dst * 256;
    #pragma unroll 1
    for (int d = 0; d < 8; ++d) {
        float t[64];
        const float4* b2p = reinterpret_cast<const float4*>(fc_b2 + d * 64);
        #pragma unroll
        for (int q = 0; q < 16; ++q) {
            float4 v = b2p[q];
            t[q * 4 + 0] = v.x; t[q * 4 + 1] = v.y;
            t[q * 4 + 2] = v.z; t[q * 4 + 3] = v.w;
        }
        for (int k = 0; k < HH; ++k) {
            float hv = hlds[k * EBS + threadIdx.x];
            const float4* wp = reinterpret_cast<const float4*>(fc_w2 + (size_t)k * 512 + d * 64);
            #pragma unroll
            for (int q = 0; q < 16; ++q) {
                float4 w = wp[q];
                t[q * 4 + 0] += hv * w.x;
                t[q * 4 + 1] += hv * w.y;
                t[q * 4 + 2] += hv * w.z;
                t[q * 4 + 3] += hv * w.w;
            }
        }
        #pragma unroll
        for (int c = 0; c < CC; ++c) {
            #pragma unroll
            for (int o = 0; o < 8; ++o) {
                float acc = 0.f;
                #pragma unroll
                for (int i = 0; i < 8; ++i) acc += xs[c * 8 + i] * t[i * 8 + o];
                atomicAdd(outp + c * 64 + d * 8 + o, acc);
            }
        }
    }
}

// ---------------------------------------------------------------------------
// Kernel C: final lin2 + self-connection, in place on out.
// ---------------------------------------------------------------------------
__global__ __launch_bounds__(256) void k_node_out(
    const float* __restrict__ node_input, const float* __restrict__ node_attr,
    const float* __restrict__ W_sc, const float* __restrict__ W_lin2,
    float* __restrict__ out, int n_nc)
{
    const float c_s = 0.3826834323650898f;
    const float c_x_scaled = 0.9238795325112867f * 0.35355339059327373f; // c_x / sqrt(8)
    int t = blockIdx.x * 256 + threadIdx.x;
    if (t >= n_nc) return;
    int n = t >> 2;
    float attr[16];
    #pragma unroll
    for (int a = 0; a < 16; ++a) attr[a] = node_attr[(size_t)n * 16 + a];

    float w2n[64];
    #pragma unroll
    for (int m = 0; m < 64; ++m) w2n[m] = 0.f;
    #pragma unroll
    for (int o = 0; o < 8; ++o) {
        #pragma unroll
        for (int a = 0; a < 16; ++a) {
            float fa = attr[a];
            #pragma unroll
            for (int p = 0; p < 8; ++p)
                w2n[o * 8 + p] += fa * W_lin2[(o * 16 + a) * 8 + p];
        }
    }
    float s[8] = {0.f, 0.f, 0.f, 0.f, 0.f, 0.f, 0.f, 0.f};
    #pragma unroll
    for (int i = 0; i < 8; ++i) {
        float vi = node_input[(size_t)t * 8 + i];
        #pragma unroll
        for (int a = 0; a < 16; ++a) {
            float f = vi * attr[a];
            #pragma unroll
            for (int o = 0; o < 8; ++o)
                s[o] += f * W_sc[(i * 16 + a) * 8 + o];
        }
    }
    float* rowp = out + (size_t)t * 64;
    #pragma unroll 1
    for (int d = 0; d < 8; ++d) {
        float aggv[8];
        #pragma unroll
        for (int o = 0; o < 8; ++o) aggv[o] = rowp[d * 8 + o];
        #pragma unroll
        for (int p = 0; p < 8; ++p) {
            float acc = 0.f;
            #pragma unroll
            for (int o = 0; o < 8; ++o) acc += aggv[o] * w2n[o * 8 + p];
            rowp[d * 8 + p] = c_s * s[p] + c_x_scaled * acc;
        }
    }
}

// ---------------------------------------------------------------------------
extern "C" void kernel_launch(void* const* d_in, const int* in_sizes, int n_in,
                              void* d_out, int out_size, void* d_ws, size_t ws_size,
                              hipStream_t stream)
{
    const float* node_input    = (const float*)d_in[0];
    const float* node_attr     = (const float*)d_in[1];
    const float* edge_features = (const float*)d_in[2];
    const float* W_sc          = (const float*)d_in[3];
    const float* W_lin1        = (const float*)d_in[4];
    const float* W_lin2        = (const float*)d_in[5];
    const float* fc_w1         = (const float*)d_in[6];
    const float* fc_b1         = (const float*)d_in[7];
    const float* fc_w2         = (const float*)d_in[8];
    const float* fc_b2         = (const float*)d_in[9];
    const int*   edge_src      = (const int*)d_in[10];
    const int*   edge_dst      = (const int*)d_in[11];

    const int N = in_sizes[1] / 16;        // node count
    const int E = in_sizes[10];            // edge count
    const int n_nc = N * CC;

    char* ws = (char*)d_ws;
    size_t off = 0;
    auto take = [&](size_t bytes) { char* p = ws + off; off += (bytes + 15) & ~(size_t)15; return p; };
    float* xbuf            = (float*)take((size_t)N * 32 * sizeof(float));
    int*   counts          = (int*)take((size_t)N * sizeof(int));
    int*   offsets         = (int*)take((size_t)N * sizeof(int));
    int*   cursor          = (int*)take((size_t)N * sizeof(int));
    int*   perm            = (int*)take((size_t)E * sizeof(int));
    unsigned short* msgbuf = (unsigned short*)take((size_t)E * 256 * sizeof(unsigned short));
    bool fast = (off <= ws_size);

    float* out = (float*)d_out;

    // node prep: x = lin1(node_input, node_attr)
    k_lin1<<<(n_nc + 255) / 256, 256, 0, stream>>>(node_input, node_attr, W_lin1, xbuf, n_nc);

    if (fast) {
        // CSR build over edge_dst
        hipMemsetAsync(counts, 0, (size_t)N * sizeof(int), stream);
        k_hist<<<(E + 255) / 256, 256, 0, stream>>>(edge_dst, counts, E);
        k_scan<<<1, 1024, 0, stream>>>(counts, offsets, cursor, N);
        k_fill<<<(E + 255) / 256, 256, 0, stream>>>(edge_dst, cursor, perm, E);
        // per-edge compute -> msg (bf16, no atomics)
        k_edge_msg<<<(E + EBS - 1) / EBS, EBS, 0, stream>>>(
            edge_features, fc_w1, fc_b1, fc_w2, fc_b2, edge_src, xbuf, msgbuf, E);
        // per-node gather-reduce -> agg (writes every element of out)
        k_gather<<<(N + 3) / 4, 256, 0, stream>>>(msgbuf, perm, offsets, counts, out, N);
    } else {
        // fallback: atomic scatter directly into out
        hipMemsetAsync(d_out, 0, (size_t)out_size * sizeof(float), stream);
        k_edge_atomic<<<(E + EBS - 1) / EBS, EBS, 0, stream>>>(
            edge_features, fc_w1, fc_b1, fc_w2, fc_b2, edge_src, edge_dst, xbuf, out, E);
    }

    // final lin2 + self-connection (in place on out)
    k_node_out<<<(n_nc + 255) / 256, 256, 0, stream>>>(node_input, node_attr, W_sc, W_lin2, out, n_nc);
}

// Round 3
// 605.967 us; speedup vs baseline: 8.7901x; 1.8340x over previous
//
#include <hip/hip_runtime.h>
#include <math.h>

// Problem dims (fixed by reference)
#define CC 4
#define FE 32
#define HH 64
#define EBS 256

typedef __attribute__((ext_vector_type(8))) short bf16x8;
typedef __attribute__((ext_vector_type(4))) float f32x4;

// bf16 round-to-nearest-even pack
__device__ inline unsigned short f2bf(float f) {
    unsigned u = __float_as_uint(f);
    u += 0x7fffu + ((u >> 16) & 1u);
    return (unsigned short)(u >> 16);
}
__device__ inline float bf2f(unsigned short b) {
    return __uint_as_float(((unsigned)b) << 16);
}

// ---------------------------------------------------------------------------
// Kernel A: x[n,c,j] = sum_{i,a} node_input[n,c,i] * node_attr[n,a] * W_lin1[i,a,j]
// ---------------------------------------------------------------------------
__global__ __launch_bounds__(256) void k_lin1(
    const float* __restrict__ node_input, const float* __restrict__ node_attr,
    const float* __restrict__ W_lin1, float* __restrict__ xout, int n_nc)
{
    int t = blockIdx.x * 256 + threadIdx.x;
    if (t >= n_nc) return;
    int n = t >> 2;
    float attr[16];
    #pragma unroll
    for (int a = 0; a < 16; ++a) attr[a] = node_attr[(size_t)n * 16 + a];
    float xi[8];
    #pragma unroll
    for (int i = 0; i < 8; ++i) xi[i] = node_input[(size_t)t * 8 + i];
    float xo[8] = {0.f, 0.f, 0.f, 0.f, 0.f, 0.f, 0.f, 0.f};
    #pragma unroll
    for (int i = 0; i < 8; ++i) {
        #pragma unroll
        for (int a = 0; a < 16; ++a) {
            float f = xi[i] * attr[a];
            #pragma unroll
            for (int j = 0; j < 8; ++j)
                xo[j] += f * W_lin1[(i * 16 + a) * 8 + j];
        }
    }
    #pragma unroll
    for (int j = 0; j < 8; ++j) xout[(size_t)t * 8 + j] = xo[j];
}

// ---------------------------------------------------------------------------
// CSR build over edge_dst
// ---------------------------------------------------------------------------
__global__ __launch_bounds__(256) void k_hist(
    const int* __restrict__ edge_dst, int* __restrict__ counts, int E)
{
    int e = blockIdx.x * 256 + threadIdx.x;
    if (e < E) atomicAdd(&counts[edge_dst[e]], 1);
}

__global__ __launch_bounds__(1024) void k_scan(
    const int* __restrict__ counts, int* __restrict__ offsets,
    int* __restrict__ cursor, int N)
{
    __shared__ int buf[1024];
    __shared__ int s_carry;
    int tid = threadIdx.x;
    if (tid == 0) s_carry = 0;
    __syncthreads();
    for (int base = 0; base < N; base += 1024) {
        int idx = base + tid;
        int v = (idx < N) ? counts[idx] : 0;
        buf[tid] = v;
        __syncthreads();
        #pragma unroll 1
        for (int s = 1; s < 1024; s <<= 1) {
            int add = (tid >= s) ? buf[tid - s] : 0;
            __syncthreads();
            buf[tid] += add;
            __syncthreads();
        }
        int incl = buf[tid];
        int carry = s_carry;
        if (idx < N) {
            int excl = carry + incl - v;
            offsets[idx] = excl;
            cursor[idx] = excl;
        }
        __syncthreads();
        if (tid == 1023) s_carry = carry + incl;
        __syncthreads();
    }
}

__global__ __launch_bounds__(256) void k_fill(
    const int* __restrict__ edge_dst, int* __restrict__ cursor,
    int* __restrict__ perm, int E)
{
    int e = blockIdx.x * 256 + threadIdx.x;
    if (e < E) {
        int pos = atomicAdd(&cursor[edge_dst[e]], 1);
        perm[pos] = e;
    }
}

// ---------------------------------------------------------------------------
// Pack W2 into MFMA B-fragment order (bf16).
// B[kappa][nu] = fc_w2[k*512 + d*64 + i*8 + o], kappa=k*8+i (0..511), nu=d*8+o (0..63)
// Fragment layout for 16x16x32: lane l holds B[kk*32 + (l>>4)*8 + j][ct*16 + (l&15)]
// Bfrag index = ((kk*4+ct)*64 + lane)*8 + j
// ---------------------------------------------------------------------------
__global__ __launch_bounds__(256) void k_prep_bfrag(
    const float* __restrict__ fc_w2, unsigned short* __restrict__ Bfrag)
{
    int t = blockIdx.x * 256 + threadIdx.x;   // 512*64 threads
    if (t >= 512 * 64) return;
    int kappa = t >> 6, nu = t & 63;
    int k = kappa >> 3, i = kappa & 7, d = nu >> 3, o = nu & 7;
    float val = fc_w2[(size_t)k * 512 + d * 64 + i * 8 + o];
    int kk = kappa >> 5;
    int lane = ((kappa >> 3) & 3) * 16 + (nu & 15);
    int ct = nu >> 4;
    int j = kappa & 7;
    Bfrag[(size_t)((kk * 4 + ct) * 64 + lane) * 8 + j] = f2bf(val);
}

// ---------------------------------------------------------------------------
// Z build: one wave per node. lane k owns h[e,k]; accumulates
//   z[c][i] = sum_{e->n} h[e,k] * x[src_e, c, i]   (32 fp32 regs)
//   xsown   = sum_{e->n} x[src_e, lane&31]
// Writes Z[(n,c), k*8+i] bf16 (coalesced dwordx4) and xsum[n,32].
// ---------------------------------------------------------------------------
__global__ __launch_bounds__(256) void k_zbuild(
    const float* __restrict__ edge_features,
    const float* __restrict__ fc_w1, const float* __restrict__ fc_b1,
    const int* __restrict__ perm, const int* __restrict__ offsets,
    const int* __restrict__ counts, const int* __restrict__ edge_src,
    const float* __restrict__ xin,
    unsigned short* __restrict__ Z, float* __restrict__ xsum,
    int n0, int nNodes)
{
    int node_l = blockIdx.x * 4 + (threadIdx.x >> 6);
    int lane = threadIdx.x & 63;
    if (node_l >= nNodes) return;
    int node = n0 + node_l;

    // preload W1 column for this lane (lane-coalesced)
    float w1c[FE];
    #pragma unroll
    for (int f = 0; f < FE; ++f) w1c[f] = fc_w1[(size_t)f * HH + lane];
    float b1 = fc_b1[lane];

    float z[CC][8];
    #pragma unroll
    for (int c = 0; c < CC; ++c)
        #pragma unroll
        for (int i = 0; i < 8; ++i) z[c][i] = 0.f;
    float xsown = 0.f;

    int off = offsets[node], cnt = counts[node];
    for (int jj = 0; jj < cnt; ++jj) {
        int e = perm[off + jj];
        int src = edge_src[e];
        // h[lane] = silu(b1 + ef[e,:] . W1[:,lane])
        float efv[FE];
        const float4* efp = reinterpret_cast<const float4*>(edge_features + (size_t)e * FE);
        #pragma unroll
        for (int q = 0; q < FE / 4; ++q) {
            float4 v = efp[q];
            efv[q * 4 + 0] = v.x; efv[q * 4 + 1] = v.y;
            efv[q * 4 + 2] = v.z; efv[q * 4 + 3] = v.w;
        }
        float pre = b1;
        #pragma unroll
        for (int f = 0; f < FE; ++f) pre += efv[f] * w1c[f];
        float hk = pre / (1.f + __expf(-pre));
        // x[src] (uniform float4 loads)
        float xs[32];
        const float4* xp = reinterpret_cast<const float4*>(xin + (size_t)src * 32);
        #pragma unroll
        for (int q = 0; q < 8; ++q) {
            float4 v = xp[q];
            xs[q * 4 + 0] = v.x; xs[q * 4 + 1] = v.y;
            xs[q * 4 + 2] = v.z; xs[q * 4 + 3] = v.w;
        }
        #pragma unroll
        for (int c = 0; c < CC; ++c)
            #pragma unroll
            for (int i = 0; i < 8; ++i)
                z[c][i] += hk * xs[c * 8 + i];
        xsown += xin[(size_t)src * 32 + (lane & 31)];
    }

    // write Z rows: row m = node_l*4 + c, lane writes cols [lane*8, lane*8+8)
    #pragma unroll
    for (int c = 0; c < CC; ++c) {
        uint4 pk;
        pk.x = (unsigned)f2bf(z[c][0]) | ((unsigned)f2bf(z[c][1]) << 16);
        pk.y = (unsigned)f2bf(z[c][2]) | ((unsigned)f2bf(z[c][3]) << 16);
        pk.z = (unsigned)f2bf(z[c][4]) | ((unsigned)f2bf(z[c][5]) << 16);
        pk.w = (unsigned)f2bf(z[c][6]) | ((unsigned)f2bf(z[c][7]) << 16);
        reinterpret_cast<uint4*>(Z)[(size_t)(node_l * 4 + c) * 64 + lane] = pk;
    }
    if (lane < 32) xsum[(size_t)node * 32 + lane] = xsown;
}

// ---------------------------------------------------------------------------
// GEMM: agg[M,64] = Z[M,512] @ W2r[512,64], bf16 MFMA 16x16x32, fp32 out.
// Block = 4 waves, M-tile 64 (wave w: rows w*16..+15), all 64 cols (4 ct tiles).
// B staged in LDS (64 KB, fragment order).
// ---------------------------------------------------------------------------
__global__ __launch_bounds__(256) void k_gemm(
    const unsigned short* __restrict__ Z, const unsigned short* __restrict__ Bfrag,
    float* __restrict__ out, int row_base, int M)
{
    __shared__ short blds[32768];   // 64 KB
    int tid = threadIdx.x;
    #pragma unroll
    for (int it = 0; it < 16; ++it) {
        int idx = it * 256 + tid;   // 4096 uint4 total
        reinterpret_cast<uint4*>(blds)[idx] = reinterpret_cast<const uint4*>(Bfrag)[idx];
    }
    __syncthreads();

    int w = tid >> 6, l = tid & 63;
    int rbase = blockIdx.x * 64 + w * 16;
    int arow = rbase + (l & 15);
    if (arow >= M) arow = M - 1;   // clamp loads; stores guarded below

    f32x4 acc[4];
    #pragma unroll
    for (int ct = 0; ct < 4; ++ct) acc[ct] = (f32x4){0.f, 0.f, 0.f, 0.f};

    #pragma unroll
    for (int kk = 0; kk < 16; ++kk) {
        uint4 av = reinterpret_cast<const uint4*>(Z)[(size_t)arow * 64 + kk * 4 + (l >> 4)];
        bf16x8 a = *reinterpret_cast<bf16x8*>(&av);
        #pragma unroll
        for (int ct = 0; ct < 4; ++ct) {
            bf16x8 b = *reinterpret_cast<const bf16x8*>(&blds[(size_t)((kk * 4 + ct) * 64 + l) * 8]);
            acc[ct] = __builtin_amdgcn_mfma_f32_16x16x32_bf16(a, b, acc[ct], 0, 0, 0);
        }
    }

    #pragma unroll
    for (int ct = 0; ct < 4; ++ct) {
        #pragma unroll
        for (int v = 0; v < 4; ++v) {
            int r = rbase + (l >> 4) * 4 + v;
            if (r < M)
                out[(size_t)(row_base + r) * 64 + ct * 16 + (l & 15)] = acc[ct][v];
        }
    }
}

// ---------------------------------------------------------------------------
// Fallback edge kernel (global atomics) — only if ws too small.
// ---------------------------------------------------------------------------
__global__ __launch_bounds__(EBS) void k_edge_atomic(
    const float* __restrict__ edge_features,
    const float* __restrict__ fc_w1, const float* __restrict__ fc_b1,
    const float* __restrict__ fc_w2, const float* __restrict__ fc_b2,
    const int* __restrict__ edge_src, const int* __restrict__ edge_dst,
    const float* __restrict__ xin, float* __restrict__ agg, int E)
{
    __shared__ float hlds[HH * EBS];
    int e = blockIdx.x * EBS + threadIdx.x;
    if (e >= E) return;
    float h[HH];
    #pragma unroll
    for (int k = 0; k < HH; ++k) h[k] = fc_b1[k];
    const float4* efp = reinterpret_cast<const float4*>(edge_features + (size_t)e * FE);
    #pragma unroll
    for (int fq = 0; fq < FE / 4; ++fq) {
        float4 efv = efp[fq];
        float ev[4] = {efv.x, efv.y, efv.z, efv.w};
        #pragma unroll
        for (int fs = 0; fs < 4; ++fs) {
            float evv = ev[fs];
            const float4* w1p = reinterpret_cast<const float4*>(fc_w1 + (fq * 4 + fs) * HH);
            #pragma unroll
            for (int q = 0; q < HH / 4; ++q) {
                float4 w = w1p[q];
                h[q * 4 + 0] += evv * w.x;
                h[q * 4 + 1] += evv * w.y;
                h[q * 4 + 2] += evv * w.z;
                h[q * 4 + 3] += evv * w.w;
            }
        }
    }
    #pragma unroll
    for (int k = 0; k < HH; ++k) {
        float v = h[k];
        hlds[k * EBS + threadIdx.x] = v / (1.f + __expf(-v));
    }
    int src = edge_src[e], dst = edge_dst[e];
    float xs[32];
    const float4* xp = reinterpret_cast<const float4*>(xin + (size_t)src * 32);
    #pragma unroll
    for (int q = 0; q < 8; ++q) {
        float4 v = xp[q];
        xs[q * 4 + 0] = v.x; xs[q * 4 + 1] = v.y;
        xs[q * 4 + 2] = v.z; xs[q * 4 + 3] = v.w;
    }
    float* outp = agg + (size_t)dst * 256;
    #pragma unroll 1
    for (int d = 0; d < 8; ++d) {
        float t[64];
        const float4* b2p = reinterpret_cast<const float4*>(fc_b2 + d * 64);
        #pragma unroll
        for (int q = 0; q < 16; ++q) {
            float4 v = b2p[q];
            t[q * 4 + 0] = v.x; t[q * 4 + 1] = v.y;
            t[q * 4 + 2] = v.z; t[q * 4 + 3] = v.w;
        }
        for (int k = 0; k < HH; ++k) {
            float hv = hlds[k * EBS + threadIdx.x];
            const float4* wp = reinterpret_cast<const float4*>(fc_w2 + (size_t)k * 512 + d * 64);
            #pragma unroll
            for (int q = 0; q < 16; ++q) {
                float4 w = wp[q];
                t[q * 4 + 0] += hv * w.x;
                t[q * 4 + 1] += hv * w.y;
                t[q * 4 + 2] += hv * w.z;
                t[q * 4 + 3] += hv * w.w;
            }
        }
        #pragma unroll
        for (int c = 0; c < CC; ++c) {
            #pragma unroll
            for (int o = 0; o < 8; ++o) {
                float acc = 0.f;
                #pragma unroll
                for (int i = 0; i < 8; ++i) acc += xs[c * 8 + i] * t[i * 8 + o];
                atomicAdd(outp + c * 64 + d * 8 + o, acc);
            }
        }
    }
}

// ---------------------------------------------------------------------------
// Kernel C: final lin2 + self-connection (+ optional b2-bias via xsum), in place.
// ---------------------------------------------------------------------------
__global__ __launch_bounds__(256) void k_node_out(
    const float* __restrict__ node_input, const float* __restrict__ node_attr,
    const float* __restrict__ W_sc, const float* __restrict__ W_lin2,
    const float* __restrict__ fc_b2, const float* __restrict__ xsum,
    float* __restrict__ out, int n_nc, int use_xsum)
{
    const float c_s = 0.3826834323650898f;
    const float c_x_scaled = 0.9238795325112867f * 0.35355339059327373f; // c_x / sqrt(8)
    int t = blockIdx.x * 256 + threadIdx.x;
    if (t >= n_nc) return;
    int n = t >> 2;
    int c = t & 3;
    float attr[16];
    #pragma unroll
    for (int a = 0; a < 16; ++a) attr[a] = node_attr[(size_t)n * 16 + a];

    float w2n[64];
    #pragma unroll
    for (int m = 0; m < 64; ++m) w2n[m] = 0.f;
    #pragma unroll
    for (int o = 0; o < 8; ++o) {
        #pragma unroll
        for (int a = 0; a < 16; ++a) {
            float fa = attr[a];
            #pragma unroll
            for (int p = 0; p < 8; ++p)
                w2n[o * 8 + p] += fa * W_lin2[(o * 16 + a) * 8 + p];
        }
    }
    float s[8] = {0.f, 0.f, 0.f, 0.f, 0.f, 0.f, 0.f, 0.f};
    #pragma unroll
    for (int i = 0; i < 8; ++i) {
        float vi = node_input[(size_t)t * 8 + i];
        #pragma unroll
        for (int a = 0; a < 16; ++a) {
            float f = vi * attr[a];
            #pragma unroll
            for (int o = 0; o < 8; ++o)
                s[o] += f * W_sc[(i * 16 + a) * 8 + o];
        }
    }
    float xbar[8];
    #pragma unroll
    for (int i = 0; i < 8; ++i)
        xbar[i] = use_xsum ? xsum[(size_t)n * 32 + c * 8 + i] : 0.f;

    float* rowp = out + (size_t)t * 64;
    #pragma unroll 1
    for (int d = 0; d < 8; ++d) {
        float aggv[8];
        #pragma unroll
        for (int o = 0; o < 8; ++o) aggv[o] = rowp[d * 8 + o];
        if (use_xsum) {
            // + sum_i xbar[i] * b2[d,i,o]
            #pragma unroll
            for (int i = 0; i < 8; ++i) {
                float xb = xbar[i];
                #pragma unroll
                for (int o = 0; o < 8; ++o)
                    aggv[o] += xb * fc_b2[d * 64 + i * 8 + o];
            }
        }
        #pragma unroll
        for (int p = 0; p < 8; ++p) {
            float acc = 0.f;
            #pragma unroll
            for (int o = 0; o < 8; ++o) acc += aggv[o] * w2n[o * 8 + p];
            rowp[d * 8 + p] = c_s * s[p] + c_x_scaled * acc;
        }
    }
}

// ---------------------------------------------------------------------------
extern "C" void kernel_launch(void* const* d_in, const int* in_sizes, int n_in,
                              void* d_out, int out_size, void* d_ws, size_t ws_size,
                              hipStream_t stream)
{
    const float* node_input    = (const float*)d_in[0];
    const float* node_attr     = (const float*)d_in[1];
    const float* edge_features = (const float*)d_in[2];
    const float* W_sc          = (const float*)d_in[3];
    const float* W_lin1        = (const float*)d_in[4];
    const float* W_lin2        = (const float*)d_in[5];
    const float* fc_w1         = (const float*)d_in[6];
    const float* fc_b1         = (const float*)d_in[7];
    const float* fc_w2         = (const float*)d_in[8];
    const float* fc_b2         = (const float*)d_in[9];
    const int*   edge_src      = (const int*)d_in[10];
    const int*   edge_dst      = (const int*)d_in[11];

    const int N = in_sizes[1] / 16;
    const int E = in_sizes[10];
    const int n_nc = N * CC;

    char* ws = (char*)d_ws;
    size_t off = 0;
    auto take = [&](size_t bytes) { char* p = ws + off; off += (bytes + 15) & ~(size_t)15; return p; };
    float* xbuf            = (float*)take((size_t)N * 32 * sizeof(float));
    int*   counts          = (int*)take((size_t)N * sizeof(int));
    int*   offsets         = (int*)take((size_t)N * sizeof(int));
    int*   cursor          = (int*)take((size_t)N * sizeof(int));
    int*   perm            = (int*)take((size_t)E * sizeof(int));
    float* xsum            = (float*)take((size_t)N * 32 * sizeof(float));
    unsigned short* Bfrag  = (unsigned short*)take((size_t)512 * 64 * sizeof(unsigned short));
    size_t fixed_off = off;
    unsigned short* Zbuf   = (unsigned short*)(ws + fixed_off);

    // nodes per pass given remaining ws (4 rows/node * 512 cols * 2B = 4096 B/node)
    long long avail = (long long)ws_size - (long long)fixed_off;
    int npp = (avail > 0) ? (int)(avail / 4096) : 0;
    bool fast = (npp >= 64);

    float* out = (float*)d_out;

    // x = lin1(node_input, node_attr)
    k_lin1<<<(n_nc + 255) / 256, 256, 0, stream>>>(node_input, node_attr, W_lin1, xbuf, n_nc);

    if (fast) {
        if (npp > N) npp = N;
        int passes = (N + npp - 1) / npp;
        npp = (N + passes - 1) / passes;   // balance passes

        // CSR over edge_dst
        hipMemsetAsync(counts, 0, (size_t)N * sizeof(int), stream);
        k_hist<<<(E + 255) / 256, 256, 0, stream>>>(edge_dst, counts, E);
        k_scan<<<1, 1024, 0, stream>>>(counts, offsets, cursor, N);
        k_fill<<<(E + 255) / 256, 256, 0, stream>>>(edge_dst, cursor, perm, E);
        // pack W2 into B-fragment order
        k_prep_bfrag<<<(512 * 64 + 255) / 256, 256, 0, stream>>>(fc_w2, Bfrag);

        for (int p = 0; p < passes; ++p) {
            int n0 = p * npp;
            int nn = (n0 + npp <= N) ? npp : (N - n0);
            int M = nn * 4;
            k_zbuild<<<(nn + 3) / 4, 256, 0, stream>>>(
                edge_features, fc_w1, fc_b1, perm, offsets, counts, edge_src,
                xbuf, Zbuf, xsum, n0, nn);
            k_gemm<<<(M + 63) / 64, 256, 0, stream>>>(Zbuf, Bfrag, out, n0 * 4, M);
        }
        k_node_out<<<(n_nc + 255) / 256, 256, 0, stream>>>(
            node_input, node_attr, W_sc, W_lin2, fc_b2, xsum, out, n_nc, 1);
    } else {
        hipMemsetAsync(d_out, 0, (size_t)out_size * sizeof(float), stream);
        k_edge_atomic<<<(E + EBS - 1) / EBS, EBS, 0, stream>>>(
            edge_features, fc_w1, fc_b1, fc_w2, fc_b2, edge_src, edge_dst, xbuf, out, E);
        k_node_out<<<(n_nc + 255) / 256, 256, 0, stream>>>(
            node_input, node_attr, W_sc, W_lin2, fc_b2, xsum, out, n_nc, 0);
    }
}

// Round 4
// 494.027 us; speedup vs baseline: 10.7819x; 1.2266x over previous
//
#include <hip/hip_runtime.h>
#include <math.h>

// Problem dims (fixed by reference)
#define CC 4
#define FE 32
#define HH 64
#define EBS 256

typedef __attribute__((ext_vector_type(8))) short bf16x8;
typedef __attribute__((ext_vector_type(4))) float f32x4;

// bf16 round-to-nearest-even pack
__device__ inline unsigned short f2bf(float f) {
    unsigned u = __float_as_uint(f);
    u += 0x7fffu + ((u >> 16) & 1u);
    return (unsigned short)(u >> 16);
}
__device__ inline float bf2f(unsigned short b) {
    return __uint_as_float(((unsigned)b) << 16);
}

// ---------------------------------------------------------------------------
// Kernel A: x[n,c,j] = sum_{i,a} node_input[n,c,i] * node_attr[n,a] * W_lin1[i,a,j]
// ---------------------------------------------------------------------------
__global__ __launch_bounds__(256) void k_lin1(
    const float* __restrict__ node_input, const float* __restrict__ node_attr,
    const float* __restrict__ W_lin1, float* __restrict__ xout, int n_nc)
{
    int t = blockIdx.x * 256 + threadIdx.x;
    if (t >= n_nc) return;
    int n = t >> 2;
    float attr[16];
    #pragma unroll
    for (int a = 0; a < 16; ++a) attr[a] = node_attr[(size_t)n * 16 + a];
    float xi[8];
    #pragma unroll
    for (int i = 0; i < 8; ++i) xi[i] = node_input[(size_t)t * 8 + i];
    float xo[8] = {0.f, 0.f, 0.f, 0.f, 0.f, 0.f, 0.f, 0.f};
    #pragma unroll
    for (int i = 0; i < 8; ++i) {
        #pragma unroll
        for (int a = 0; a < 16; ++a) {
            float f = xi[i] * attr[a];
            #pragma unroll
            for (int j = 0; j < 8; ++j)
                xo[j] += f * W_lin1[(i * 16 + a) * 8 + j];
        }
    }
    #pragma unroll
    for (int j = 0; j < 8; ++j) xout[(size_t)t * 8 + j] = xo[j];
}

// ---------------------------------------------------------------------------
// CSR build over edge_dst
// ---------------------------------------------------------------------------
__global__ __launch_bounds__(256) void k_hist(
    const int* __restrict__ edge_dst, int* __restrict__ counts, int E)
{
    int e = blockIdx.x * 256 + threadIdx.x;
    if (e < E) atomicAdd(&counts[edge_dst[e]], 1);
}

// single-block shfl-based scan (16 waves of 64)
__global__ __launch_bounds__(1024) void k_scan(
    const int* __restrict__ counts, int* __restrict__ offsets,
    int* __restrict__ cursor, int N)
{
    __shared__ int wsum[16];
    __shared__ int wpre[16];
    __shared__ int s_tot;
    __shared__ int s_carry;
    int tid = threadIdx.x, wid = tid >> 6, lane = tid & 63;
    if (tid == 0) s_carry = 0;
    __syncthreads();
    for (int base = 0; base < N; base += 1024) {
        int idx = base + tid;
        int v = (idx < N) ? counts[idx] : 0;
        int x = v;
        #pragma unroll
        for (int s = 1; s < 64; s <<= 1) {
            int y = __shfl_up(x, s);
            if (lane >= s) x += y;
        }
        if (lane == 63) wsum[wid] = x;
        __syncthreads();
        if (wid == 0) {
            int wv = (lane < 16) ? wsum[lane] : 0;
            int wx = wv;
            #pragma unroll
            for (int s = 1; s < 16; s <<= 1) {
                int y = __shfl_up(wx, s);
                if (lane >= s) wx += y;
            }
            if (lane < 16) wpre[lane] = wx - wv;
            if (lane == 15) s_tot = wx;
        }
        __syncthreads();
        if (idx < N) {
            int excl = s_carry + wpre[wid] + (x - v);
            offsets[idx] = excl;
            cursor[idx] = excl;
        }
        __syncthreads();
        if (tid == 0) s_carry += s_tot;
    }
}

// fill permutation; also gather srcs into perm order
__global__ __launch_bounds__(256) void k_fill(
    const int* __restrict__ edge_dst, const int* __restrict__ edge_src,
    int* __restrict__ cursor, int* __restrict__ perm, int* __restrict__ srcs, int E)
{
    int e = blockIdx.x * 256 + threadIdx.x;
    if (e < E) {
        int pos = atomicAdd(&cursor[edge_dst[e]], 1);
        perm[pos] = e;
        srcs[pos] = edge_src[e];
    }
}

// ---------------------------------------------------------------------------
// Pack W2 into MFMA B-fragment order (bf16).
// ---------------------------------------------------------------------------
__global__ __launch_bounds__(256) void k_prep_bfrag(
    const float* __restrict__ fc_w2, unsigned short* __restrict__ Bfrag)
{
    int t = blockIdx.x * 256 + threadIdx.x;
    if (t >= 512 * 64) return;
    int kappa = t >> 6, nu = t & 63;
    int k = kappa >> 3, i = kappa & 7, d = nu >> 3, o = nu & 7;
    float val = fc_w2[(size_t)k * 512 + d * 64 + i * 8 + o];
    int kk = kappa >> 5;
    int lane = ((kappa >> 3) & 3) * 16 + (nu & 15);
    int ct = nu >> 4;
    int j = kappa & 7;
    Bfrag[(size_t)((kk * 4 + ct) * 64 + lane) * 8 + j] = f2bf(val);
}

// ---------------------------------------------------------------------------
// H build: H[p, k] = silu(ef[perm[p],:] . W1[:,k] + b1[k]) as bf16, perm order.
// One thread per permuted edge; W1/b1 staged in LDS; coalesced H writes.
// ---------------------------------------------------------------------------
__global__ __launch_bounds__(256) void k_hsilu(
    const float* __restrict__ edge_features,
    const float* __restrict__ fc_w1, const float* __restrict__ fc_b1,
    const int* __restrict__ perm,
    unsigned short* __restrict__ H, int E)
{
    __shared__ float w1lds[FE * HH];
    __shared__ float b1lds[HH];
    int tid = threadIdx.x;
    #pragma unroll
    for (int it = 0; it < (FE * HH) / 256; ++it)
        w1lds[it * 256 + tid] = fc_w1[it * 256 + tid];
    if (tid < HH) b1lds[tid] = fc_b1[tid];
    __syncthreads();

    int p = blockIdx.x * 256 + tid;
    if (p >= E) return;
    int e = perm[p];

    float efv[FE];
    const float4* efp = reinterpret_cast<const float4*>(edge_features + (size_t)e * FE);
    #pragma unroll
    for (int q = 0; q < FE / 4; ++q) {
        float4 v = efp[q];
        efv[q * 4 + 0] = v.x; efv[q * 4 + 1] = v.y;
        efv[q * 4 + 2] = v.z; efv[q * 4 + 3] = v.w;
    }
    float h[HH];
    #pragma unroll
    for (int k = 0; k < HH; ++k) h[k] = b1lds[k];
    #pragma unroll
    for (int f = 0; f < FE; ++f) {
        float ev = efv[f];
        const float4* wp = reinterpret_cast<const float4*>(&w1lds[f * HH]);
        #pragma unroll
        for (int q = 0; q < HH / 4; ++q) {
            float4 w = wp[q];
            h[q * 4 + 0] += ev * w.x;
            h[q * 4 + 1] += ev * w.y;
            h[q * 4 + 2] += ev * w.z;
            h[q * 4 + 3] += ev * w.w;
        }
    }
    unsigned short* Hrow = H + (size_t)p * HH;
    #pragma unroll
    for (int q = 0; q < 8; ++q) {
        float s0 = h[q * 8 + 0], s1 = h[q * 8 + 1], s2 = h[q * 8 + 2], s3 = h[q * 8 + 3];
        float s4 = h[q * 8 + 4], s5 = h[q * 8 + 5], s6 = h[q * 8 + 6], s7 = h[q * 8 + 7];
        s0 /= (1.f + __expf(-s0)); s1 /= (1.f + __expf(-s1));
        s2 /= (1.f + __expf(-s2)); s3 /= (1.f + __expf(-s3));
        s4 /= (1.f + __expf(-s4)); s5 /= (1.f + __expf(-s5));
        s6 /= (1.f + __expf(-s6)); s7 /= (1.f + __expf(-s7));
        uint4 pk;
        pk.x = (unsigned)f2bf(s0) | ((unsigned)f2bf(s1) << 16);
        pk.y = (unsigned)f2bf(s2) | ((unsigned)f2bf(s3) << 16);
        pk.z = (unsigned)f2bf(s4) | ((unsigned)f2bf(s5) << 16);
        pk.w = (unsigned)f2bf(s6) | ((unsigned)f2bf(s7) << 16);
        reinterpret_cast<uint4*>(Hrow)[q] = pk;
    }
}

// ---------------------------------------------------------------------------
// Z build: one wave per node. lane k owns h[e,k]; accumulates
//   z[c][i] = sum_{e->n} h[e,k] * x[src_e, c, i]
// H read coalesced (128B/edge); srcs preloaded by lanes + shfl (no dep chain).
// ---------------------------------------------------------------------------
__global__ __launch_bounds__(256) void k_zbuild(
    const unsigned short* __restrict__ H, const int* __restrict__ srcs,
    const int* __restrict__ offsets, const int* __restrict__ counts,
    const float* __restrict__ xin,
    unsigned short* __restrict__ Z, float* __restrict__ xsum,
    int n0, int nNodes)
{
    int node_l = blockIdx.x * 4 + (threadIdx.x >> 6);
    int lane = threadIdx.x & 63;
    if (node_l >= nNodes) return;
    int node = n0 + node_l;
    int off = offsets[node], cnt = counts[node];

    float z[CC][8];
    #pragma unroll
    for (int c = 0; c < CC; ++c)
        #pragma unroll
        for (int i = 0; i < 8; ++i) z[c][i] = 0.f;
    float xsown = 0.f;

    for (int base = 0; base < cnt; base += 64) {
        int m = (cnt - base < 64) ? (cnt - base) : 64;
        int sj = (lane < m) ? srcs[off + base + lane] : 0;
        for (int j = 0; j < m; ++j) {
            int src = __shfl(sj, j);
            float hk = bf2f(H[(size_t)(off + base + j) * HH + lane]);
            const float4* xp = reinterpret_cast<const float4*>(xin + (size_t)src * 32);
            float xs[32];
            #pragma unroll
            for (int q = 0; q < 8; ++q) {
                float4 v = xp[q];
                xs[q * 4 + 0] = v.x; xs[q * 4 + 1] = v.y;
                xs[q * 4 + 2] = v.z; xs[q * 4 + 3] = v.w;
            }
            #pragma unroll
            for (int c = 0; c < CC; ++c)
                #pragma unroll
                for (int i = 0; i < 8; ++i)
                    z[c][i] += hk * xs[c * 8 + i];
            xsown += xin[(size_t)src * 32 + (lane & 31)];
        }
    }

    #pragma unroll
    for (int c = 0; c < CC; ++c) {
        uint4 pk;
        pk.x = (unsigned)f2bf(z[c][0]) | ((unsigned)f2bf(z[c][1]) << 16);
        pk.y = (unsigned)f2bf(z[c][2]) | ((unsigned)f2bf(z[c][3]) << 16);
        pk.z = (unsigned)f2bf(z[c][4]) | ((unsigned)f2bf(z[c][5]) << 16);
        pk.w = (unsigned)f2bf(z[c][6]) | ((unsigned)f2bf(z[c][7]) << 16);
        reinterpret_cast<uint4*>(Z)[(size_t)(node_l * 4 + c) * 64 + lane] = pk;
    }
    if (lane < 32) xsum[(size_t)node * 32 + lane] = xsown;
}

// ---------------------------------------------------------------------------
// GEMM: agg[M,64] = Z[M,512] @ W2r[512,64], bf16 MFMA 16x16x32, fp32 out.
// ---------------------------------------------------------------------------
__global__ __launch_bounds__(256) void k_gemm(
    const unsigned short* __restrict__ Z, const unsigned short* __restrict__ Bfrag,
    float* __restrict__ out, int row_base, int M)
{
    __shared__ short blds[32768];
    int tid = threadIdx.x;
    #pragma unroll
    for (int it = 0; it < 16; ++it) {
        int idx = it * 256 + tid;
        reinterpret_cast<uint4*>(blds)[idx] = reinterpret_cast<const uint4*>(Bfrag)[idx];
    }
    __syncthreads();

    int w = tid >> 6, l = tid & 63;
    int rbase = blockIdx.x * 64 + w * 16;
    int arow = rbase + (l & 15);
    if (arow >= M) arow = M - 1;

    f32x4 acc[4];
    #pragma unroll
    for (int ct = 0; ct < 4; ++ct) acc[ct] = (f32x4){0.f, 0.f, 0.f, 0.f};

    #pragma unroll
    for (int kk = 0; kk < 16; ++kk) {
        uint4 av = reinterpret_cast<const uint4*>(Z)[(size_t)arow * 64 + kk * 4 + (l >> 4)];
        bf16x8 a = *reinterpret_cast<bf16x8*>(&av);
        #pragma unroll
        for (int ct = 0; ct < 4; ++ct) {
            bf16x8 b = *reinterpret_cast<const bf16x8*>(&blds[(size_t)((kk * 4 + ct) * 64 + l) * 8]);
            acc[ct] = __builtin_amdgcn_mfma_f32_16x16x32_bf16(a, b, acc[ct], 0, 0, 0);
        }
    }

    #pragma unroll
    for (int ct = 0; ct < 4; ++ct) {
        #pragma unroll
        for (int v = 0; v < 4; ++v) {
            int r = rbase + (l >> 4) * 4 + v;
            if (r < M)
                out[(size_t)(row_base + r) * 64 + ct * 16 + (l & 15)] = acc[ct][v];
        }
    }
}

// ---------------------------------------------------------------------------
// Fallback edge kernel (global atomics) — only if ws too small.
// ---------------------------------------------------------------------------
__global__ __launch_bounds__(EBS) void k_edge_atomic(
    const float* __restrict__ edge_features,
    const float* __restrict__ fc_w1, const float* __restrict__ fc_b1,
    const float* __restrict__ fc_w2, const float* __restrict__ fc_b2,
    const int* __restrict__ edge_src, const int* __restrict__ edge_dst,
    const float* __restrict__ xin, float* __restrict__ agg, int E)
{
    __shared__ float hlds[HH * EBS];
    int e = blockIdx.x * EBS + threadIdx.x;
    if (e >= E) return;
    float h[HH];
    #pragma unroll
    for (int k = 0; k < HH; ++k) h[k] = fc_b1[k];
    const float4* efp = reinterpret_cast<const float4*>(edge_features + (size_t)e * FE);
    #pragma unroll
    for (int fq = 0; fq < FE / 4; ++fq) {
        float4 efv = efp[fq];
        float ev[4] = {efv.x, efv.y, efv.z, efv.w};
        #pragma unroll
        for (int fs = 0; fs < 4; ++fs) {
            float evv = ev[fs];
            const float4* w1p = reinterpret_cast<const float4*>(fc_w1 + (fq * 4 + fs) * HH);
            #pragma unroll
            for (int q = 0; q < HH / 4; ++q) {
                float4 w = w1p[q];
                h[q * 4 + 0] += evv * w.x;
                h[q * 4 + 1] += evv * w.y;
                h[q * 4 + 2] += evv * w.z;
                h[q * 4 + 3] += evv * w.w;
            }
        }
    }
    #pragma unroll
    for (int k = 0; k < HH; ++k) {
        float v = h[k];
        hlds[k * EBS + threadIdx.x] = v / (1.f + __expf(-v));
    }
    int src = edge_src[e], dst = edge_dst[e];
    float xs[32];
    const float4* xp = reinterpret_cast<const float4*>(xin + (size_t)src * 32);
    #pragma unroll
    for (int q = 0; q < 8; ++q) {
        float4 v = xp[q];
        xs[q * 4 + 0] = v.x; xs[q * 4 + 1] = v.y;
        xs[q * 4 + 2] = v.z; xs[q * 4 + 3] = v.w;
    }
    float* outp = agg + (size_t)dst * 256;
    #pragma unroll 1
    for (int d = 0; d < 8; ++d) {
        float t[64];
        const float4* b2p = reinterpret_cast<const float4*>(fc_b2 + d * 64);
        #pragma unroll
        for (int q = 0; q < 16; ++q) {
            float4 v = b2p[q];
            t[q * 4 + 0] = v.x; t[q * 4 + 1] = v.y;
            t[q * 4 + 2] = v.z; t[q * 4 + 3] = v.w;
        }
        for (int k = 0; k < HH; ++k) {
            float hv = hlds[k * EBS + threadIdx.x];
            const float4* wp = reinterpret_cast<const float4*>(fc_w2 + (size_t)k * 512 + d * 64);
            #pragma unroll
            for (int q = 0; q < 16; ++q) {
                float4 w = wp[q];
                t[q * 4 + 0] += hv * w.x;
                t[q * 4 + 1] += hv * w.y;
                t[q * 4 + 2] += hv * w.z;
                t[q * 4 + 3] += hv * w.w;
            }
        }
        #pragma unroll
        for (int c = 0; c < CC; ++c) {
            #pragma unroll
            for (int o = 0; o < 8; ++o) {
                float acc = 0.f;
                #pragma unroll
                for (int i = 0; i < 8; ++i) acc += xs[c * 8 + i] * t[i * 8 + o];
                atomicAdd(outp + c * 64 + d * 8 + o, acc);
            }
        }
    }
}

// ---------------------------------------------------------------------------
// Kernel C: final lin2 + self-connection (+ b2-bias via xsum), in place.
// ---------------------------------------------------------------------------
__global__ __launch_bounds__(256) void k_node_out(
    const float* __restrict__ node_input, const float* __restrict__ node_attr,
    const float* __restrict__ W_sc, const float* __restrict__ W_lin2,
    const float* __restrict__ fc_b2, const float* __restrict__ xsum,
    float* __restrict__ out, int n_nc, int use_xsum)
{
    const float c_s = 0.3826834323650898f;
    const float c_x_scaled = 0.9238795325112867f * 0.35355339059327373f;
    int t = blockIdx.x * 256 + threadIdx.x;
    if (t >= n_nc) return;
    int n = t >> 2;
    int c = t & 3;
    float attr[16];
    #pragma unroll
    for (int a = 0; a < 16; ++a) attr[a] = node_attr[(size_t)n * 16 + a];

    float w2n[64];
    #pragma unroll
    for (int m = 0; m < 64; ++m) w2n[m] = 0.f;
    #pragma unroll
    for (int o = 0; o < 8; ++o) {
        #pragma unroll
        for (int a = 0; a < 16; ++a) {
            float fa = attr[a];
            #pragma unroll
            for (int p = 0; p < 8; ++p)
                w2n[o * 8 + p] += fa * W_lin2[(o * 16 + a) * 8 + p];
        }
    }
    float s[8] = {0.f, 0.f, 0.f, 0.f, 0.f, 0.f, 0.f, 0.f};
    #pragma unroll
    for (int i = 0; i < 8; ++i) {
        float vi = node_input[(size_t)t * 8 + i];
        #pragma unroll
        for (int a = 0; a < 16; ++a) {
            float f = vi * attr[a];
            #pragma unroll
            for (int o = 0; o < 8; ++o)
                s[o] += f * W_sc[(i * 16 + a) * 8 + o];
        }
    }
    float xbar[8];
    #pragma unroll
    for (int i = 0; i < 8; ++i)
        xbar[i] = use_xsum ? xsum[(size_t)n * 32 + c * 8 + i] : 0.f;

    float* rowp = out + (size_t)t * 64;
    #pragma unroll 1
    for (int d = 0; d < 8; ++d) {
        float aggv[8];
        #pragma unroll
        for (int o = 0; o < 8; ++o) aggv[o] = rowp[d * 8 + o];
        if (use_xsum) {
            #pragma unroll
            for (int i = 0; i < 8; ++i) {
                float xb = xbar[i];
                #pragma unroll
                for (int o = 0; o < 8; ++o)
                    aggv[o] += xb * fc_b2[d * 64 + i * 8 + o];
            }
        }
        #pragma unroll
        for (int p = 0; p < 8; ++p) {
            float acc = 0.f;
            #pragma unroll
            for (int o = 0; o < 8; ++o) acc += aggv[o] * w2n[o * 8 + p];
            rowp[d * 8 + p] = c_s * s[p] + c_x_scaled * acc;
        }
    }
}

// ---------------------------------------------------------------------------
extern "C" void kernel_launch(void* const* d_in, const int* in_sizes, int n_in,
                              void* d_out, int out_size, void* d_ws, size_t ws_size,
                              hipStream_t stream)
{
    const float* node_input    = (const float*)d_in[0];
    const float* node_attr     = (const float*)d_in[1];
    const float* edge_features = (const float*)d_in[2];
    const float* W_sc          = (const float*)d_in[3];
    const float* W_lin1        = (const float*)d_in[4];
    const float* W_lin2        = (const float*)d_in[5];
    const float* fc_w1         = (const float*)d_in[6];
    const float* fc_b1         = (const float*)d_in[7];
    const float* fc_w2         = (const float*)d_in[8];
    const float* fc_b2         = (const float*)d_in[9];
    const int*   edge_src      = (const int*)d_in[10];
    const int*   edge_dst      = (const int*)d_in[11];

    const int N = in_sizes[1] / 16;
    const int E = in_sizes[10];
    const int n_nc = N * CC;

    char* ws = (char*)d_ws;
    size_t off = 0;
    auto take = [&](size_t bytes) { char* p = ws + off; off += (bytes + 15) & ~(size_t)15; return p; };
    float* xbuf            = (float*)take((size_t)N * 32 * sizeof(float));
    int*   counts          = (int*)take((size_t)N * sizeof(int));
    int*   offsets         = (int*)take((size_t)N * sizeof(int));
    int*   cursor          = (int*)take((size_t)N * sizeof(int));
    int*   perm            = (int*)take((size_t)E * sizeof(int));
    int*   srcs            = (int*)take((size_t)E * sizeof(int));
    float* xsum            = (float*)take((size_t)N * 32 * sizeof(float));
    unsigned short* Bfrag  = (unsigned short*)take((size_t)512 * 64 * sizeof(unsigned short));
    unsigned short* Hbuf   = (unsigned short*)take((size_t)E * HH * sizeof(unsigned short));
    size_t fixed_off = off;
    unsigned short* Zbuf   = (unsigned short*)(ws + fixed_off);

    long long avail = (long long)ws_size - (long long)fixed_off;
    int npp = (avail > 0) ? (int)(avail / 4096) : 0;   // 4 rows * 512 cols * 2B per node
    bool fast = (npp >= 64);

    float* out = (float*)d_out;

    // x = lin1(node_input, node_attr)
    k_lin1<<<(n_nc + 255) / 256, 256, 0, stream>>>(node_input, node_attr, W_lin1, xbuf, n_nc);

    if (fast) {
        if (npp > N) npp = N;
        int passes = (N + npp - 1) / npp;
        npp = (N + passes - 1) / passes;

        // CSR over edge_dst (+ srcs gather)
        hipMemsetAsync(counts, 0, (size_t)N * sizeof(int), stream);
        k_hist<<<(E + 255) / 256, 256, 0, stream>>>(edge_dst, counts, E);
        k_scan<<<1, 1024, 0, stream>>>(counts, offsets, cursor, N);
        k_fill<<<(E + 255) / 256, 256, 0, stream>>>(edge_dst, edge_src, cursor, perm, srcs, E);
        // radial layer-1 for all edges, perm order
        k_hsilu<<<(E + 255) / 256, 256, 0, stream>>>(edge_features, fc_w1, fc_b1, perm, Hbuf, E);
        // pack W2 into B-fragment order
        k_prep_bfrag<<<(512 * 64 + 255) / 256, 256, 0, stream>>>(fc_w2, Bfrag);

        for (int p = 0; p < passes; ++p) {
            int n0 = p * npp;
            int nn = (n0 + npp <= N) ? npp : (N - n0);
            int M = nn * 4;
            k_zbuild<<<(nn + 3) / 4, 256, 0, stream>>>(
                Hbuf, srcs, offsets, counts, xbuf, Zbuf, xsum, n0, nn);
            k_gemm<<<(M + 63) / 64, 256, 0, stream>>>(Zbuf, Bfrag, out, n0 * 4, M);
        }
        k_node_out<<<(n_nc + 255) / 256, 256, 0, stream>>>(
            node_input, node_attr, W_sc, W_lin2, fc_b2, xsum, out, n_nc, 1);
    } else {
        hipMemsetAsync(d_out, 0, (size_t)out_size * sizeof(float), stream);
        k_edge_atomic<<<(E + EBS - 1) / EBS, EBS, 0, stream>>>(
            edge_features, fc_w1, fc_b1, fc_w2, fc_b2, edge_src, edge_dst, xbuf, out, E);
        k_node_out<<<(n_nc + 255) / 256, 256, 0, stream>>>(
            node_input, node_attr, W_sc, W_lin2, fc_b2, xsum, out, n_nc, 0);
    }
}